// Round 13
// baseline (145.297 us; speedup 1.0000x reference)
//
#include <hip/hip_runtime.h>
#include <math.h>

#define BB 8
#define TT 4096
#define DD 2048
#define QF 512                // floats per quarter-row
#define THREADS 512           // 8 waves; wave w owns batch row b=w
#define NT 4                  // t-steps per block
#define NBLK (TT / NT)        // 1024 blocks -> 4 resident/CU (36KB LDS each)
#define NG (NT * 4)           // quarter-steps per block
#define SMEM_BYTES ((2 * BB * QF + 2 * QF) * 4)   // 36864 B

typedef float v4f __attribute__((ext_vector_type(4)));

__device__ __forceinline__ float gelu_fast(float x) {
    // gelu(x) = x * sigmoid(2c*(x + 0.044715 x^3)); saturates correctly.
    const float c1 = 1.5957691216057308f;    // 2*sqrt(2/pi)
    const float c2 = 0.07135481282556483f;   // 2c*0.044715
    float e = __expf(-x * fmaf(c2, x * x, c1));
    return x * __builtin_amdgcn_rcpf(1.0f + e);
}

__device__ __forceinline__ void gl2lds16(const float* g, float* l) {
    __builtin_amdgcn_global_load_lds(
        (const __attribute__((address_space(1))) void*)g,
        (__attribute__((address_space(3))) void*)l, 16, 0, 0);
}
__device__ __forceinline__ void gl2lds4(const float* g, float* l) {
    __builtin_amdgcn_global_load_lds(
        (const __attribute__((address_space(1))) void*)g,
        (__attribute__((address_space(3))) void*)l, 4, 0, 0);
}

__global__ __launch_bounds__(THREADS, 8) void gelu275_fused(
    const float* __restrict__ x,          // [B,T,D]
    const float* __restrict__ log_k_pos,  // [1]
    const float* __restrict__ pos_buf,    // [T,D]
    const float* __restrict__ pos_facil,  // [T]
    float* __restrict__ out)              // [B,T,D]
{
    extern __shared__ __align__(16) float smem[];
    // layout: xb0[8][512] | xb1[8][512] | pb0[512] | pb1[512]
    float* const xb0 = smem;
    float* const xb1 = smem + BB * QF;
    float* const pb0 = smem + 2 * BB * QF;
    float* const pb1 = pb0 + QF;
    __shared__ float s_red[17];           // single-buffered (barrier-protected)

    const int tid  = threadIdx.x;
    const int lane = tid & 63;
    const int wave = tid >> 6;            // == batch row b
    const int t0   = blockIdx.x * NT;
    const int base = lane * 4;

    const float kp = fminf(fmaxf(__expf(log_k_pos[0]), 0.01f), 5.0f);

    const float* xrow = x       + ((size_t)wave * TT + t0) * DD;
    const float* prow = pos_buf + (size_t)t0 * DD;
    float*       orow = out     + ((size_t)wave * TT + t0) * DD;

    // prologue: issue quarter g=0 (t0,q0): 2 x-loads + 1 pos-load per wave
    gl2lds16(xrow + base,        xb0 + wave * QF);
    gl2lds16(xrow + 256 + base,  xb0 + wave * QF + 256);
    gl2lds4 (prow + wave * 64 + lane, pb0 + wave * 64);

    v4f Y[8];                             // full-row y, filled across 4 quarters
    float dot = 0.f, yn2 = 0.f, pn2 = 0.f;

#pragma unroll
    for (int g = 0; g < NG; ++g) {
        const int tl = g >> 2;
        const int q  = g & 3;
        float* const xc = (g & 1) ? xb1 : xb0;
        float* const pc = (g & 1) ? pb1 : pb0;

        // 1) issue NEXT quarter's 3 loads (its buffer was freed by the exit
        //    barrier of quarter g-1; the read queue never empties)
        if (g + 1 < NG) {
            const int   gn = g + 1;
            float* const xn = (gn & 1) ? xb1 : xb0;
            float* const pn = (gn & 1) ? pb1 : pb0;
            const float* xs = xrow + (size_t)(gn >> 2) * DD + (gn & 3) * QF;
            const float* ps = prow + (size_t)(gn >> 2) * DD + (gn & 3) * QF;
            gl2lds16(xs + base,       xn + wave * QF);
            gl2lds16(xs + 256 + base, xn + wave * QF + 256);
            gl2lds4 (ps + wave * 64 + lane, pn + wave * 64);
        }

        // 2) counted wait for THIS quarter's 3 loads (in-order vmcnt:
        //    immediate = #VMEM ops issued after them). q0 steady: 8 stores +
        //    3 next-loads = 11; q1..q3: 3; first: 3; last: 0.
        if (g == 0)           { asm volatile("s_waitcnt vmcnt(3)"  ::: "memory"); }
        else if (g == NG - 1) { asm volatile("s_waitcnt vmcnt(0)"  ::: "memory"); }
        else if (q == 0)      { asm volatile("s_waitcnt vmcnt(11)" ::: "memory"); }
        else                  { asm volatile("s_waitcnt vmcnt(3)"  ::: "memory"); }
        __builtin_amdgcn_s_barrier();
        asm volatile("" ::: "memory");

        // 3) compute this quarter from LDS (own row + shared pos quarter)
        if (q == 0) { dot = 0.f; yn2 = 0.f; pn2 = 0.f; }
#pragma unroll
        for (int c = 0; c < 2; ++c) {
            v4f v       = *(const v4f*)(xc + wave * QF + c * 256 + base);
            const v4f p = *(const v4f*)(pc + c * 256 + base);
            v.x = gelu_fast(v.x); v.y = gelu_fast(v.y);
            v.z = gelu_fast(v.z); v.w = gelu_fast(v.w);
            Y[q * 2 + c] = v;
            dot += v.x * p.x + v.y * p.y + v.z * p.z + v.w * p.w;
            yn2 += v.x * v.x + v.y * v.y + v.z * v.z + v.w * v.w;
            pn2 += p.x * p.x + p.y * p.y + p.z * p.z + p.w * p.w;
        }

        // 4) after q3: full-row butterfly reduce, publish to LDS
        if (q == 3) {
#pragma unroll
            for (int off = 32; off; off >>= 1) {
                dot += __shfl_xor(dot, off);
                yn2 += __shfl_xor(yn2, off);
                pn2 += __shfl_xor(pn2, off);
            }
            if (lane == 0) {
                s_red[wave]     = dot;
                s_red[8 + wave] = yn2;
                if (wave == 0) s_red[16] = pn2;
            }
        }

        // 5) exit barrier: LDS-only drain keeps DMA prefetch in flight;
        //    frees buf[g&1] and (q3) publishes s_red
        asm volatile("s_waitcnt lgkmcnt(0)" ::: "memory");
        __builtin_amdgcn_s_barrier();
        asm volatile("" ::: "memory");

        // 6) after q3: gate + 8 stores of the full row
        if (q == 3) {
            const float pnn = fmaxf(sqrtf(s_red[16]), 1e-12f);
            float simsum = 0.f, simw = 0.f;
#pragma unroll
            for (int bb = 0; bb < BB; ++bb) {
                const float s = s_red[bb] *
                    __builtin_amdgcn_rcpf(
                        fmaxf(sqrtf(s_red[8 + bb]), 1e-12f) * pnn);
                simsum += s;
                if (bb == wave) simw = s;
            }
            const bool  fire  = (simsum * 0.125f) > 0.85f;
            const float pf    = pos_facil[t0 + tl];   // wave-uniform s_load
            const float facil = fire ? fminf(pf * 2.0f, 16.0f) : pf;
            const float gt    = fminf(1.0f + kp * (facil - 1.0f) * simw, 8.0f);

            float* o = orow + (size_t)tl * DD;
#pragma unroll
            for (int k = 0; k < 8; ++k) {
                v4f ov = Y[k];
                ov.x *= gt; ov.y *= gt; ov.z *= gt; ov.w *= gt;
                *(v4f*)(o + (k >> 1) * QF + (k & 1) * 256 + base) = ov;
            }
        }
    }
}

extern "C" void kernel_launch(void* const* d_in, const int* in_sizes, int n_in,
                              void* d_out, int out_size, void* d_ws, size_t ws_size,
                              hipStream_t stream) {
    const float* x          = (const float*)d_in[0];
    const float* log_k_pos  = (const float*)d_in[1];
    const float* pos_buf    = (const float*)d_in[2];
    const float* pos_facil  = (const float*)d_in[3];
    float* out              = (float*)d_out;

    dim3 grid(NBLK);
    dim3 block(THREADS);
    gelu275_fused<<<grid, block, SMEM_BYTES, stream>>>(
        x, log_k_pos, pos_buf, pos_facil, out);
}

// Round 14
// 121.438 us; speedup vs baseline: 1.1965x; 1.1965x over previous
//
#include <hip/hip_runtime.h>
#include <math.h>

#define BB 8
#define TT 4096
#define DD 2048
#define HALF 1024             // floats per half-row
#define THREADS 512           // 8 waves; wave w owns batch row b=w
#define NT 8                  // t-steps per block
#define NBLK (TT / NT)        // 512 blocks -> 2 resident/CU (72KB LDS each)
#define NG (NT * 2)           // half-steps per block
#define SMEM_BYTES ((2 * BB * HALF + 2 * HALF) * 4)   // 73728 B

typedef float v4f __attribute__((ext_vector_type(4)));

__device__ __forceinline__ float gelu_fast(float x) {
    // gelu(x) = x * sigmoid(2c*(x + 0.044715 x^3)); saturates correctly.
    const float c1 = 1.5957691216057308f;    // 2*sqrt(2/pi)
    const float c2 = 0.07135481282556483f;   // 2c*0.044715
    float e = __expf(-x * fmaf(c2, x * x, c1));
    return x * __builtin_amdgcn_rcpf(1.0f + e);
}

__device__ __forceinline__ void gl2lds16(const float* g, float* l) {
    __builtin_amdgcn_global_load_lds(
        (const __attribute__((address_space(1))) void*)g,
        (__attribute__((address_space(3))) void*)l, 16, 0, 0);
}
__device__ __forceinline__ void gl2lds4(const float* g, float* l) {
    __builtin_amdgcn_global_load_lds(
        (const __attribute__((address_space(1))) void*)g,
        (__attribute__((address_space(3))) void*)l, 4, 0, 0);
}

__global__ __launch_bounds__(THREADS, 4) void gelu275_fused(
    const float* __restrict__ x,          // [B,T,D]
    const float* __restrict__ log_k_pos,  // [1]
    const float* __restrict__ pos_buf,    // [T,D]
    const float* __restrict__ pos_facil,  // [T]
    float* __restrict__ out)              // [B,T,D]
{
    extern __shared__ __align__(16) float smem[];
    // layout: xbuf0[8][1024] | xbuf1[8][1024] | pbuf0[1024] | pbuf1[1024]
    float* const xbuf0 = smem;
    float* const xbuf1 = smem + BB * HALF;
    float* const pbuf0 = smem + 2 * BB * HALF;
    float* const pbuf1 = pbuf0 + HALF;
    __shared__ float s_red[17];           // single-buffered (barrier-protected)

    const int tid  = threadIdx.x;
    const int lane = tid & 63;
    const int wave = tid >> 6;            // == batch row b
    const int t0   = blockIdx.x * NT;
    const int base = lane * 4;

    const float kp = fminf(fmaxf(__expf(log_k_pos[0]), 0.01f), 5.0f);
    // uniform-address scalar loads (lgkm, not vmcnt) -> ledger stays exact
    float pfv[NT];
#pragma unroll
    for (int i = 0; i < NT; ++i) pfv[i] = pos_facil[t0 + i];

    const float* xrow = x       + ((size_t)wave * TT + t0) * DD;
    const float* prow = pos_buf + (size_t)t0 * DD;
    float*       orow = out     + ((size_t)wave * TT + t0) * DD;

    // prologue: issue half g=0 (t0, h=0): 4 x-loads + 2 pos-loads per wave
    {
#pragma unroll
        for (int c = 0; c < 4; ++c)
            gl2lds16(xrow + c * 256 + base, xbuf0 + wave * HALF + c * 256);
        gl2lds4(prow + wave * 128 + lane,      pbuf0 + wave * 128);
        gl2lds4(prow + wave * 128 + 64 + lane, pbuf0 + wave * 128 + 64);
    }

    v4f Y[8];                             // full-row y, filled across 2 halves
    float dot = 0.f, yn2 = 0.f, pn2 = 0.f;

#pragma unroll
    for (int g = 0; g < NG; ++g) {
        const int tloc = g >> 1;
        const int h    = g & 1;
        float* const xc = h ? xbuf1 : xbuf0;
        float* const pc = h ? pbuf1 : pbuf0;

        // 1) issue NEXT half's 6 loads (its buffer was freed by the exit
        //    barrier of half g-1; read queue never empties)
        if (g + 1 < NG) {
            const int tn = (g + 1) >> 1;
            const int hn = (g + 1) & 1;
            float* const xn = hn ? xbuf1 : xbuf0;
            float* const pn = hn ? pbuf1 : pbuf0;
            const float* xs = xrow + (size_t)tn * DD + hn * HALF;
            const float* pp = prow + (size_t)tn * DD + hn * HALF;
#pragma unroll
            for (int c = 0; c < 4; ++c)
                gl2lds16(xs + c * 256 + base, xn + wave * HALF + c * 256);
            gl2lds4(pp + wave * 128 + lane,      pn + wave * 128);
            gl2lds4(pp + wave * 128 + 64 + lane, pn + wave * 128 + 64);
        }

        // 2) counted wait for THIS half's 6 loads (issued one half-step ago).
        //    In-order vmcnt decrement => immediate = #ops issued after them:
        //    h0 steady: 8 stores + 6 next-loads = 14; h1: 6; first: 6; last: 0.
        if (g == 0)           { asm volatile("s_waitcnt vmcnt(6)"  ::: "memory"); }
        else if (g == NG - 1) { asm volatile("s_waitcnt vmcnt(0)"  ::: "memory"); }
        else if (h == 0)      { asm volatile("s_waitcnt vmcnt(14)" ::: "memory"); }
        else                  { asm volatile("s_waitcnt vmcnt(6)"  ::: "memory"); }
        __builtin_amdgcn_s_barrier();
        asm volatile("" ::: "memory");

        // 3) compute this half from LDS (own row + shared pos half)
        if (h == 0) { dot = 0.f; yn2 = 0.f; pn2 = 0.f; }
#pragma unroll
        for (int c = 0; c < 4; ++c) {
            v4f v       = *(const v4f*)(xc + wave * HALF + c * 256 + base);
            const v4f p = *(const v4f*)(pc + c * 256 + base);
            v.x = gelu_fast(v.x); v.y = gelu_fast(v.y);
            v.z = gelu_fast(v.z); v.w = gelu_fast(v.w);
            Y[h * 4 + c] = v;
            dot += v.x * p.x + v.y * p.y + v.z * p.z + v.w * p.w;
            yn2 += v.x * v.x + v.y * v.y + v.z * v.z + v.w * v.w;
            pn2 += p.x * p.x + p.y * p.y + p.z * p.z + p.w * p.w;
        }

        // 4) after h1: full-row butterfly reduce, publish to LDS
        if (h == 1) {
#pragma unroll
            for (int off = 32; off; off >>= 1) {
                dot += __shfl_xor(dot, off);
                yn2 += __shfl_xor(yn2, off);
                pn2 += __shfl_xor(pn2, off);
            }
            if (lane == 0) {
                s_red[wave]     = dot;
                s_red[8 + wave] = yn2;
                if (wave == 0) s_red[16] = pn2;
            }
        }

        // 5) exit barrier: LDS-only drain keeps prefetch in flight; frees
        //    buf[g&1] for reuse and (h1) makes s_red visible
        asm volatile("s_waitcnt lgkmcnt(0)" ::: "memory");
        __builtin_amdgcn_s_barrier();
        asm volatile("" ::: "memory");

        // 6) after h1: gate + 8 stores of the full row
        if (h == 1) {
            const float pnn = fmaxf(sqrtf(s_red[16]), 1e-12f);
            float simsum = 0.f, simw = 0.f;
#pragma unroll
            for (int bb = 0; bb < BB; ++bb) {
                const float s = s_red[bb] *
                    __builtin_amdgcn_rcpf(
                        fmaxf(sqrtf(s_red[8 + bb]), 1e-12f) * pnn);
                simsum += s;
                if (bb == wave) simw = s;
            }
            const bool  fire  = (simsum * 0.125f) > 0.85f;
            const float pf    = pfv[tloc];
            const float facil = fire ? fminf(pf * 2.0f, 16.0f) : pf;
            const float gt    = fminf(1.0f + kp * (facil - 1.0f) * simw, 8.0f);

            float* o = orow + (size_t)tloc * DD;
#pragma unroll
            for (int k = 0; k < 8; ++k) {
                v4f ov = Y[k];
                ov.x *= gt; ov.y *= gt; ov.z *= gt; ov.w *= gt;
                *(v4f*)(o + (k >> 2) * HALF + (k & 3) * 256 + base) = ov;
            }
        }
    }
}

extern "C" void kernel_launch(void* const* d_in, const int* in_sizes, int n_in,
                              void* d_out, int out_size, void* d_ws, size_t ws_size,
                              hipStream_t stream) {
    const float* x          = (const float*)d_in[0];
    const float* log_k_pos  = (const float*)d_in[1];
    const float* pos_buf    = (const float*)d_in[2];
    const float* pos_facil  = (const float*)d_in[3];
    float* out              = (float*)d_out;

    // allow >64KB dynamic LDS (idempotent; set on first (non-captured) call)
    (void)hipFuncSetAttribute((const void*)gelu275_fused,
                              hipFuncAttributeMaxDynamicSharedMemorySize,
                              SMEM_BYTES);

    dim3 grid(NBLK);
    dim3 block(THREADS);
    gelu275_fused<<<grid, block, SMEM_BYTES, stream>>>(
        x, log_k_pos, pos_buf, pos_facil, out);
}